// Round 1
// baseline (201.958 us; speedup 1.0000x reference)
//
#include <hip/hip_runtime.h>
#include <hip/hip_bf16.h>
#include <math.h>

// Problem constants (B, C, H, W = 4, 128, 64, 64)
#define BATCH 4
#define NTOK 4096          // H*W tokens
#define CDIM 128           // embed dim
#define LOG2E 1.4426950408889634f

typedef __bf16 bf16;
typedef __bf16 bf16x8 __attribute__((ext_vector_type(8)));
typedef __bf16 bf16x4 __attribute__((ext_vector_type(4)));
typedef float  f32x4  __attribute__((ext_vector_type(4)));

// ---------------------------------------------------------------------------
// Projection: Q[b,n,d] = sum_c x[b,c,n] * Wq[d,c]   (same for K, V)
// Outputs: Q, K as bf16 [B][N][C]; V transposed as bf16 [B][C][N] so the
// flash kernel's PV B-fragments are contiguous ds_read_b128.
// Grid: (64, B), block 256 (4 waves; wave w owns token rows w*16..w*16+15).
// ---------------------------------------------------------------------------
__global__ __launch_bounds__(256) void proj_kernel(
    const float* __restrict__ x,
    const float* __restrict__ Wq,
    const float* __restrict__ Wk,
    const float* __restrict__ Wv,
    bf16* __restrict__ Qg, bf16* __restrict__ Kg, bf16* __restrict__ Vtg)
{
    __shared__ bf16 t_s[64][136];        // t[n][c], +8 pad (16B-aligned rows)
    __shared__ bf16 w_s[3][128][136];    // W[m][d][c]

    const int tid = threadIdx.x;
    const int b  = blockIdx.y;
    const int n0 = blockIdx.x * 64;

    // Stage x[b, :, n0:n0+64] transposed into t_s[n][c] (bf16)
    {
        const float* xb = x + (size_t)b * CDIM * NTOK;
#pragma unroll
        for (int it = 0; it < 8; ++it) {
            int idx = it * 1024 + tid * 4;   // 8192 elements total
            int c  = idx >> 6;
            int nc = idx & 63;
            const float4 v = *(const float4*)(xb + (size_t)c * NTOK + n0 + nc);
            t_s[nc + 0][c] = (bf16)v.x;
            t_s[nc + 1][c] = (bf16)v.y;
            t_s[nc + 2][c] = (bf16)v.z;
            t_s[nc + 3][c] = (bf16)v.w;
        }
    }
    // Stage the three weight matrices (row-major [d][c]) as bf16
    {
        const float* Ws[3] = {Wq, Wk, Wv};
        for (int m = 0; m < 3; ++m) {
            const float* W = Ws[m];
#pragma unroll
            for (int it = 0; it < 16; ++it) {
                int idx = it * 1024 + tid * 4;   // 16384 elements
                int d   = idx >> 7;
                int col = idx & 127;
                const float4 v = *(const float4*)(W + d * 128 + col);
                bf16x4 t = {(bf16)v.x, (bf16)v.y, (bf16)v.z, (bf16)v.w};
                *(bf16x4*)&w_s[m][d][col] = t;
            }
        }
    }
    __syncthreads();

    const int wv   = tid >> 6;
    const int lane = tid & 63;
    const int l16  = lane & 15;
    const int quad = lane >> 4;

    // A-fragments (t rows) shared across Q/K/V and all d-blocks
    bf16x8 af[4];
#pragma unroll
    for (int kc = 0; kc < 4; ++kc)
        af[kc] = *(const bf16x8*)&t_s[wv * 16 + l16][kc * 32 + quad * 8];

    for (int m = 0; m < 3; ++m) {
#pragma unroll
        for (int dblk = 0; dblk < 8; ++dblk) {
            f32x4 acc = {0.f, 0.f, 0.f, 0.f};
#pragma unroll
            for (int kc = 0; kc < 4; ++kc) {
                bf16x8 bfR = *(const bf16x8*)&w_s[m][dblk * 16 + l16][kc * 32 + quad * 8];
                acc = __builtin_amdgcn_mfma_f32_16x16x32_bf16(af[kc], bfR, acc, 0, 0, 0);
            }
            // C/D layout: row = quad*4 + i, col = l16 (verified m89/m91)
            if (m < 2) {
                bf16* dst = (m == 0) ? Qg : Kg;
#pragma unroll
                for (int i = 0; i < 4; ++i) {
                    int r = quad * 4 + i;
                    dst[((size_t)b * NTOK + n0 + wv * 16 + r) * CDIM + dblk * 16 + l16] = (bf16)acc[i];
                }
            } else {
#pragma unroll
                for (int i = 0; i < 4; ++i) {
                    int r = quad * 4 + i;
                    Vtg[((size_t)b * CDIM + dblk * 16 + l16) * NTOK + n0 + wv * 16 + r] = (bf16)acc[i];
                }
            }
        }
    }
}

// ---------------------------------------------------------------------------
// Flash attention: per block (b, 64-row Q tile), iterate 64-row KV tiles with
// online softmax. Wave w owns Q rows w*16..w*16+15 end-to-end (running m, l,
// and O[16][128] accumulator in registers).
// scale = 1/sqrt(N) = 1/64 (faithful reference quirk).
// ---------------------------------------------------------------------------
__global__ __launch_bounds__(256) void attn_kernel(
    const bf16* __restrict__ Qg,
    const bf16* __restrict__ Kg,
    const bf16* __restrict__ Vtg,
    float* __restrict__ out)
{
    __shared__ bf16 q_s[64][136];
    __shared__ bf16 k_s[64][136];
    __shared__ bf16 vt_s[128][72];       // V^T tile: [d][kv]
    __shared__ bf16 p_s[4][16][72];      // per-wave P round-trip

    const int tid  = threadIdx.x;
    const int b    = blockIdx.y;
    const int n0   = blockIdx.x * 64;
    const int wv   = tid >> 6;
    const int lane = tid & 63;
    const int l16  = lane & 15;
    const int quad = lane >> 4;
    const float scale = 1.0f / 64.0f;    // 1/sqrt(4096)

    // Stage Q tile once
    {
        const bf16* Qb = Qg + ((size_t)b * NTOK + n0) * CDIM;
#pragma unroll
        for (int it = 0; it < 4; ++it) {
            int idx = it * 2048 + tid * 8;   // 8192 bf16
            int r = idx >> 7, c = idx & 127;
            *(bf16x8*)&q_s[r][c] = *(const bf16x8*)(Qb + idx);
        }
    }

    f32x4 o[8];
#pragma unroll
    for (int d = 0; d < 8; ++d) o[d] = (f32x4){0.f, 0.f, 0.f, 0.f};
    float m_run[4], l_run[4];
#pragma unroll
    for (int i = 0; i < 4; ++i) { m_run[i] = -1e38f; l_run[i] = 0.f; }

    __syncthreads();

    // Q A-fragments, loaded once (q_s is never overwritten)
    bf16x8 af[4];
#pragma unroll
    for (int kc = 0; kc < 4; ++kc)
        af[kc] = *(const bf16x8*)&q_s[wv * 16 + l16][kc * 32 + quad * 8];

    for (int kt = 0; kt < 64; ++kt) {
        const int kv0 = kt * 64;
        // Stage K tile [kv][c] and V^T tile [d][kv]
        {
            const bf16* Kb = Kg + ((size_t)b * NTOK + kv0) * CDIM;
#pragma unroll
            for (int it = 0; it < 4; ++it) {
                int idx = it * 2048 + tid * 8;
                int r = idx >> 7, c = idx & 127;
                *(bf16x8*)&k_s[r][c] = *(const bf16x8*)(Kb + idx);
            }
            const bf16* Vb = Vtg + (size_t)b * CDIM * NTOK + kv0;
#pragma unroll
            for (int it = 0; it < 4; ++it) {
                int idx = it * 2048 + tid * 8;
                int d = idx >> 6, c = idx & 63;
                *(bf16x8*)&vt_s[d][c] = *(const bf16x8*)(Vb + (size_t)d * NTOK + c);
            }
        }
        __syncthreads();

        // S[16][64] = Q K^T for this wave's rows
        f32x4 sa[4];
#pragma unroll
        for (int nb = 0; nb < 4; ++nb) {
            f32x4 acc = {0.f, 0.f, 0.f, 0.f};
#pragma unroll
            for (int kc = 0; kc < 4; ++kc) {
                bf16x8 bfR = *(const bf16x8*)&k_s[nb * 16 + l16][kc * 32 + quad * 8];
                acc = __builtin_amdgcn_mfma_f32_16x16x32_bf16(af[kc], bfR, acc, 0, 0, 0);
            }
            sa[nb] = acc;
        }

        // Online softmax. Row r = quad*4 + i; reduce across lanes 0..15 (same quad).
        float p[4][4];
#pragma unroll
        for (int i = 0; i < 4; ++i) {
            float rmax = -1e38f;
#pragma unroll
            for (int nb = 0; nb < 4; ++nb) {
                float v = sa[nb][i] * scale;
                p[nb][i] = v;
                rmax = fmaxf(rmax, v);
            }
#pragma unroll
            for (int off = 1; off < 16; off <<= 1)
                rmax = fmaxf(rmax, __shfl_xor(rmax, off, 64));
            float mn    = fmaxf(m_run[i], rmax);
            float alpha = __builtin_amdgcn_exp2f((m_run[i] - mn) * LOG2E);
            m_run[i] = mn;
            float rsum = 0.f;
#pragma unroll
            for (int nb = 0; nb < 4; ++nb) {
                float e = __builtin_amdgcn_exp2f((p[nb][i] - mn) * LOG2E);
                p[nb][i] = e;
                rsum += e;
            }
#pragma unroll
            for (int off = 1; off < 16; off <<= 1)
                rsum += __shfl_xor(rsum, off, 64);
            l_run[i] = l_run[i] * alpha + rsum;
#pragma unroll
            for (int d = 0; d < 8; ++d)
                o[d][i] *= alpha;
        }

        // P -> LDS (C-layout scatter), then read back as A-fragments
#pragma unroll
        for (int nb = 0; nb < 4; ++nb)
#pragma unroll
            for (int i = 0; i < 4; ++i)
                p_s[wv][quad * 4 + i][nb * 16 + l16] = (bf16)p[nb][i];
        __syncthreads();

        // O += P V  (B-fragment from vt_s: B[k=kv][n=d] = V[kv][d] = vt_s[d][kv])
#pragma unroll
        for (int kc = 0; kc < 2; ++kc) {
            bf16x8 pf = *(const bf16x8*)&p_s[wv][l16][kc * 32 + quad * 8];
#pragma unroll
            for (int d = 0; d < 8; ++d) {
                bf16x8 bfV = *(const bf16x8*)&vt_s[d * 16 + l16][kc * 32 + quad * 8];
                o[d] = __builtin_amdgcn_mfma_f32_16x16x32_bf16(pf, bfV, o[d], 0, 0, 0);
            }
        }
        __syncthreads();   // protect k_s / vt_s before next stage
    }

    // Epilogue: out[b][n0 + row][d] = O / l
    float inv_l[4];
#pragma unroll
    for (int i = 0; i < 4; ++i) inv_l[i] = 1.0f / l_run[i];
    float* ob = out + ((size_t)b * NTOK + n0) * CDIM;
#pragma unroll
    for (int d = 0; d < 8; ++d)
#pragma unroll
        for (int i = 0; i < 4; ++i)
            ob[(wv * 16 + quad * 4 + i) * CDIM + d * 16 + l16] = o[d][i] * inv_l[i];
}

// ---------------------------------------------------------------------------
extern "C" void kernel_launch(void* const* d_in, const int* in_sizes, int n_in,
                              void* d_out, int out_size, void* d_ws, size_t ws_size,
                              hipStream_t stream)
{
    const float* x  = (const float*)d_in[0];
    const float* Wq = (const float*)d_in[1];
    const float* Wk = (const float*)d_in[2];
    const float* Wv = (const float*)d_in[3];
    float* out = (float*)d_out;

    // Workspace layout: Q (4MB) | K (4MB) | V^T (4MB), all bf16
    bf16* Qg  = (bf16*)d_ws;
    bf16* Kg  = Qg + (size_t)BATCH * NTOK * CDIM;
    bf16* Vtg = Kg + (size_t)BATCH * NTOK * CDIM;

    dim3 grid(NTOK / 64, BATCH);
    dim3 blk(256);
    hipLaunchKernelGGL(proj_kernel, grid, blk, 0, stream, x, Wq, Wk, Wv, Qg, Kg, Vtg);
    hipLaunchKernelGGL(attn_kernel, grid, blk, 0, stream, Qg, Kg, Vtg, out);
}

// Round 2
// 168.158 us; speedup vs baseline: 1.2010x; 1.2010x over previous
//
#include <hip/hip_runtime.h>
#include <hip/hip_bf16.h>

#define BATCH 4
#define NTOK 4096
#define CDIM 128
#define KSCALE 0.02254211001389005f   // log2(e) / 64  (scale = 1/sqrt(4096), ref quirk)

typedef __bf16 bf16;
typedef __bf16 bf16x8 __attribute__((ext_vector_type(8)));
typedef __bf16 bf16x4 __attribute__((ext_vector_type(4)));
typedef float  f32x4  __attribute__((ext_vector_type(4)));

// ---------------------------------------------------------------------------
// Projection. grid (64 n-tiles, B, 3 matrices), block 256.
// m = blockIdx.z selects Wq/Wk/Wv. Q,K -> [B][N][C] bf16; V -> [B][C][N] bf16.
// LDS = t_s 17.4K + w_s 32K = 50K -> 3 blocks/CU (vs 1 before).
// ---------------------------------------------------------------------------
__global__ __launch_bounds__(256) void proj_kernel(
    const float* __restrict__ x, const float* __restrict__ Wq,
    const float* __restrict__ Wk, const float* __restrict__ Wv,
    bf16* __restrict__ Qg, bf16* __restrict__ Kg, bf16* __restrict__ Vtg)
{
    __shared__ bf16 t_s[64][136];     // x tile transposed; reused as vt[128][68] when m==2
    __shared__ bf16 w_s[128 * 128];   // XOR-swizzled 16B segments

    const int tid = threadIdx.x;
    const int b   = blockIdx.y;
    const int n0  = blockIdx.x * 64;
    const int m   = blockIdx.z;
    const float* W = (m == 0) ? Wq : (m == 1) ? Wk : Wv;

    // stage x[b, :, n0:n0+64] transposed -> t_s[n][c]; 4 coalesced dword loads
    // per group + one b64 LDS write (conflict-free; old version was 16-way).
    {
        const float* xb = x + (size_t)b * CDIM * NTOK + n0;
        const int n   = tid & 63;
        const int cg4 = tid >> 6;
#pragma unroll
        for (int g = 0; g < 8; ++g) {
            const int c0 = g * 16 + cg4 * 4;
            float v0 = xb[(size_t)(c0 + 0) * NTOK + n];
            float v1 = xb[(size_t)(c0 + 1) * NTOK + n];
            float v2 = xb[(size_t)(c0 + 2) * NTOK + n];
            float v3 = xb[(size_t)(c0 + 3) * NTOK + n];
            bf16x4 t = {(bf16)v0, (bf16)v1, (bf16)v2, (bf16)v3};
            *(bf16x4*)&t_s[n][c0] = t;
        }
    }
    // stage W as bf16, segment-swizzled: elem (d,c) -> seg d*16 + ((c>>3)^d)&15
    {
#pragma unroll
        for (int it = 0; it < 16; ++it) {
            const int idx = it * 1024 + tid * 4;
            const int d = idx >> 7, c = idx & 127;
            const float4 v = *(const float4*)(W + d * 128 + c);
            bf16x4 t = {(bf16)v.x, (bf16)v.y, (bf16)v.z, (bf16)v.w};
            const int seg = d * 16 + (((c >> 3) ^ d) & 15);
            *(bf16x4*)&w_s[seg * 8 + (c & 7)] = t;
        }
    }
    __syncthreads();

    const int lane = tid & 63, wv = tid >> 6;
    const int l16 = lane & 15, quad = lane >> 4;

    bf16x8 af[4];
#pragma unroll
    for (int kc = 0; kc < 4; ++kc)
        af[kc] = *(const bf16x8*)&t_s[wv * 16 + l16][kc * 32 + quad * 8];
    __syncthreads();                       // t_s region free (m==2 reuses it)

    bf16* vt_lds = &t_s[0][0];             // [128][68] view, 8704 elems exactly

#pragma unroll
    for (int dblk = 0; dblk < 8; ++dblk) {
        f32x4 acc = {0.f, 0.f, 0.f, 0.f};
#pragma unroll
        for (int kc = 0; kc < 4; ++kc) {
            const int seg = (dblk * 16 + l16) * 16 + (((kc * 4 + quad) ^ l16) & 15);
            bf16x8 bw = *(const bf16x8*)&w_s[seg * 8];
            acc = __builtin_amdgcn_mfma_f32_16x16x32_bf16(af[kc], bw, acc, 0, 0, 0);
        }
        // C/D layout: token row = quad*4+i, channel col = l16
        if (m < 2) {
            bf16* dst = (m == 0) ? Qg : Kg;
#pragma unroll
            for (int i = 0; i < 4; ++i)
                dst[((size_t)b * NTOK + n0 + wv * 16 + quad * 4 + i) * CDIM + dblk * 16 + l16] = (bf16)acc[i];
        } else {
#pragma unroll
            for (int i = 0; i < 4; ++i)
                vt_lds[(dblk * 16 + l16) * 68 + wv * 16 + quad * 4 + i] = (bf16)acc[i];
        }
    }
    if (m == 2) {
        __syncthreads();
        // coalesced V^T global write (old path was 2-byte scatter)
        const int d = tid >> 1, half = tid & 1;
#pragma unroll
        for (int j = 0; j < 4; ++j) {
            bf16x8 v = *(const bf16x8*)&vt_lds[d * 68 + half * 32 + j * 8];
            *(bf16x8*)&Vtg[((size_t)b * CDIM + d) * NTOK + n0 + half * 32 + j * 8] = v;
        }
    }
}

// ---------------------------------------------------------------------------
// Flash attention, no-max softmax (scores bounded ~|0.35|), KV-split.
// grid (64 q-tiles, B, nsplit), block 256 (4 waves, 16 rows each).
// LDS = k2 16K + vt2 16K + p_s 8K = 40960 B -> exactly 4 blocks/CU.
// All LDS tiles XOR-swizzled so every b128 access is bank-conflict-free.
// Writes UNNORMALIZED partial O (split 0 -> d_out, others -> Op) + row sums.
// ---------------------------------------------------------------------------
__global__ __launch_bounds__(256, 4) void attn_kernel(
    const bf16* __restrict__ Qg, const bf16* __restrict__ Kg,
    const bf16* __restrict__ Vtg, float* __restrict__ outO,
    float* __restrict__ Op, float* __restrict__ lsum, int nsplit)
{
    __shared__ bf16 k2[64 * 128];     // seg(r, cg^r)
    __shared__ bf16 vt2[64 * 128];    // seg(kvg*128 + (d^kvg))
    __shared__ bf16 p_s[4][16 * 64];  // per-wave, seg(row*8 + (cg^row))

    const int tid = threadIdx.x;
    const int b = blockIdx.y, sp = blockIdx.z;
    const int n0 = blockIdx.x * 64;
    const int lane = tid & 63, wv = tid >> 6;
    const int l16 = lane & 15, quad = lane >> 4;

    const int ktn = 64 / nsplit, kt0 = sp * ktn;

    // Q fragments straight from global (L2-resident, read once per block)
    bf16x8 af[4];
#pragma unroll
    for (int kc = 0; kc < 4; ++kc)
        af[kc] = *(const bf16x8*)&Qg[((size_t)b * NTOK + n0 + wv * 16 + l16) * CDIM + kc * 32 + quad * 8];

    f32x4 o[8];
#pragma unroll
    for (int d = 0; d < 8; ++d) o[d] = (f32x4){0.f, 0.f, 0.f, 0.f};
    float ls[4] = {0.f, 0.f, 0.f, 0.f};

    const int kr  = tid >> 4;    // K staging: row group
    const int kcg = tid & 15;    //            col segment
    const int vd0 = tid >> 3;    // V staging: d group
    const int vkg = tid & 7;     //            kv segment

    for (int kt = kt0; kt < kt0 + ktn; ++kt) {
        const int kv0 = kt * 64;
        const bf16* Kb = Kg + ((size_t)b * NTOK + kv0) * CDIM;
        const bf16* Vb = Vtg + (size_t)b * CDIM * NTOK + kv0;
#pragma unroll
        for (int it = 0; it < 4; ++it) {
            const int r = it * 16 + kr;
            *(bf16x8*)&k2[(r * 16 + ((kcg ^ r) & 15)) * 8] =
                *(const bf16x8*)(Kb + r * CDIM + kcg * 8);
            const int d = it * 32 + vd0;
            *(bf16x8*)&vt2[(vkg * 128 + (d ^ vkg)) * 8] =
                *(const bf16x8*)(Vb + (size_t)d * NTOK + vkg * 8);
        }
        __syncthreads();

        // S = Q K^T   (wave rows l16; cols nb*16+l16 via C-layout)
        f32x4 sa[4];
#pragma unroll
        for (int nb = 0; nb < 4; ++nb) {
            f32x4 acc = {0.f, 0.f, 0.f, 0.f};
#pragma unroll
            for (int kc = 0; kc < 4; ++kc) {
                const int r = nb * 16 + l16;
                bf16x8 bk = *(const bf16x8*)&k2[(r * 16 + (((kc * 4 + quad) ^ r) & 15)) * 8];
                acc = __builtin_amdgcn_mfma_f32_16x16x32_bf16(af[kc], bk, acc, 0, 0, 0);
            }
            sa[nb] = acc;
        }

        // p = exp2(s * log2e/64); defer row-sum reduction; scatter P to LDS
#pragma unroll
        for (int nb = 0; nb < 4; ++nb) {
#pragma unroll
            for (int i = 0; i < 4; ++i) {
                float p = __builtin_amdgcn_exp2f(sa[nb][i] * KSCALE);
                ls[i] += p;
                const int row = quad * 4 + i;
                const int col = nb * 16 + l16;
                p_s[wv][(row * 8 + (((col >> 3) ^ row) & 7)) * 8 + (col & 7)] = (bf16)p;
            }
        }

        // O += P V   (p_s is wave-private: no barrier, just lgkmcnt ordering)
#pragma unroll
        for (int kc = 0; kc < 2; ++kc) {
            const int kvg = kc * 4 + quad;
            bf16x8 pf = *(const bf16x8*)&p_s[wv][(l16 * 8 + ((kvg ^ l16) & 7)) * 8];
#pragma unroll
            for (int d = 0; d < 8; ++d) {
                bf16x8 bv = *(const bf16x8*)&vt2[(kvg * 128 + ((d * 16 + l16) ^ kvg)) * 8];
                o[d] = __builtin_amdgcn_mfma_f32_16x16x32_bf16(pf, bv, o[d], 0, 0, 0);
            }
        }
        __syncthreads();   // protect k2/vt2 before next staging
    }

    // epilogue: reduce row sums across the 16 lanes of each quad group
#pragma unroll
    for (int i = 0; i < 4; ++i) {
#pragma unroll
        for (int off = 1; off < 16; off <<= 1)
            ls[i] += __shfl_xor(ls[i], off, 64);
    }
    const size_t rowbase = (size_t)b * NTOK + n0 + wv * 16;
    if (l16 == 0) {
#pragma unroll
        for (int i = 0; i < 4; ++i)
            lsum[(size_t)sp * (BATCH * NTOK) + rowbase + quad * 4 + i] = ls[i];
    }
    float* dst = (sp == 0) ? outO : (Op + (size_t)(sp - 1) * ((size_t)BATCH * NTOK * CDIM));
#pragma unroll
    for (int d = 0; d < 8; ++d)
#pragma unroll
        for (int i = 0; i < 4; ++i)
            dst[(rowbase + quad * 4 + i) * CDIM + d * 16 + l16] = o[d][i];
}

// ---------------------------------------------------------------------------
// Combine: out = (sum of unnormalized partial O) / (sum of row sums)
// ---------------------------------------------------------------------------
__global__ __launch_bounds__(256) void combine_kernel(
    float* __restrict__ outO, const float* __restrict__ Op,
    const float* __restrict__ lsum, int nsplit)
{
    const int i = blockIdx.x * 256 + threadIdx.x;   // float4 index
    const int row = i >> 5;                          // (i*4)/128
    f32x4 a = *(f32x4*)&outO[i * 4];
    for (int s = 1; s < nsplit; ++s)
        a += *(const f32x4*)&Op[(size_t)(s - 1) * ((size_t)BATCH * NTOK * CDIM) + i * 4];
    float l = 0.f;
    for (int s = 0; s < nsplit; ++s)
        l += lsum[(size_t)s * (BATCH * NTOK) + row];
    a *= (1.0f / l);
    *(f32x4*)&outO[i * 4] = a;
}

// ---------------------------------------------------------------------------
extern "C" void kernel_launch(void* const* d_in, const int* in_sizes, int n_in,
                              void* d_out, int out_size, void* d_ws, size_t ws_size,
                              hipStream_t stream)
{
    const float* x  = (const float*)d_in[0];
    const float* Wq = (const float*)d_in[1];
    const float* Wk = (const float*)d_in[2];
    const float* Wv = (const float*)d_in[3];
    float* out = (float*)d_out;

    // ws: Q 4M | K 4M | Vt 4M | lsum 256K | Op (nsplit-1)*8M
    char* ws = (char*)d_ws;
    bf16*  Qg   = (bf16*)ws;
    bf16*  Kg   = (bf16*)(ws + (4u << 20));
    bf16*  Vtg  = (bf16*)(ws + (8u << 20));
    float* lsum = (float*)(ws + (12u << 20));
    float* Op   = (float*)(ws + (12u << 20) + (256u << 10));

    const size_t obytes = (size_t)BATCH * NTOK * CDIM * 4;
    const size_t base   = (12u << 20) + (256u << 10);
    int nsplit = (ws_size >= base + 3 * obytes) ? 4
               : (ws_size >= base + 1 * obytes) ? 2 : 1;

    hipLaunchKernelGGL(proj_kernel, dim3(64, BATCH, 3), dim3(256), 0, stream,
                       x, Wq, Wk, Wv, Qg, Kg, Vtg);
    hipLaunchKernelGGL(attn_kernel, dim3(64, BATCH, nsplit), dim3(256), 0, stream,
                       Qg, Kg, Vtg, out, Op, lsum, nsplit);
    hipLaunchKernelGGL(combine_kernel,
                       dim3((BATCH * NTOK * CDIM / 4) / 256), dim3(256), 0, stream,
                       out, Op, lsum, nsplit);
}